// Round 1
// baseline (583.238 us; speedup 1.0000x reference)
//
#include <hip/hip_runtime.h>

#define NN 50000
#define NE 800000
#define FIN 128
#define HD 64
#define SL 3

// ---------------- CSR build ----------------

__global__ void hist_k(const int* __restrict__ dst, int* __restrict__ cnt) {
    int e = blockIdx.x * blockDim.x + threadIdx.x;
    if (e < NE) atomicAdd(&cnt[dst[e]], 1);
}

__global__ __launch_bounds__(1024) void scan_k(const int* __restrict__ cnt,
                                               int* __restrict__ off,
                                               int* __restrict__ cur) {
    __shared__ int part[1024];
    int t = threadIdx.x;
    const int CH = (NN + 1023) / 1024;  // 49
    int base = t * CH;
    int s = 0;
    for (int i = 0; i < CH; i++) {
        int idx = base + i;
        if (idx < NN) s += cnt[idx];
    }
    part[t] = s;
    __syncthreads();
    // Hillis-Steele inclusive scan
    for (int d = 1; d < 1024; d <<= 1) {
        int v = (t >= d) ? part[t - d] : 0;
        __syncthreads();
        part[t] += v;
        __syncthreads();
    }
    int prefix = (t > 0) ? part[t - 1] : 0;
    for (int i = 0; i < CH; i++) {
        int idx = base + i;
        if (idx < NN) {
            off[idx] = prefix;
            cur[idx] = prefix;
            prefix += cnt[idx];
        }
    }
    if (t == 1023) off[NN] = prefix;
}

__global__ void fill_k(const int* __restrict__ src, const int* __restrict__ dst,
                       const float* __restrict__ attr, int* __restrict__ cur,
                       int* __restrict__ csrc, float* __restrict__ cattr) {
    int e = blockIdx.x * blockDim.x + threadIdx.x;
    if (e < NE) {
        int d = dst[e];
        int p = atomicAdd(&cur[d], 1);
        csrc[p]  = src[e];
        cattr[p] = attr[e];
    }
}

// ---------------- scatter: m[n] = sum_{e: dst=n} attr[e] * h[src[e]] ----------------
// wave per dst node; lane = feature. No atomics: CSR gives exclusive writes.

__global__ __launch_bounds__(256) void scatter_k(const float* __restrict__ h,
                                                 const int* __restrict__ off,
                                                 const int* __restrict__ csrc,
                                                 const float* __restrict__ cattr,
                                                 float* __restrict__ m) {
    int w    = (blockIdx.x * blockDim.x + threadIdx.x) >> 6;
    int lane = threadIdx.x & 63;
    if (w >= NN) return;
    int s = off[w], e = off[w + 1];
    float acc = 0.f;
    int i = s;
    for (; i + 4 <= e; i += 4) {
        int   s0 = csrc[i],     s1 = csrc[i + 1], s2 = csrc[i + 2], s3 = csrc[i + 3];
        float a0 = cattr[i],    a1 = cattr[i + 1], a2 = cattr[i + 2], a3 = cattr[i + 3];
        float v0 = h[(size_t)s0 * HD + lane];
        float v1 = h[(size_t)s1 * HD + lane];
        float v2 = h[(size_t)s2 * HD + lane];
        float v3 = h[(size_t)s3 * HD + lane];
        acc += a0 * v0;
        acc += a1 * v1;
        acc += a2 * v2;
        acc += a3 * v3;
    }
    for (; i < e; ++i) acc += cattr[i] * h[(size_t)csrc[i] * HD + lane];
    m[(size_t)w * HD + lane] = acc;
}

// ---------------- conv GEMM stage: out = [hprev +] relu(m@W1+b1)@W2+b2 ----------------

__device__ __forceinline__ float f4get(const float4 v, int k) {
    return k == 0 ? v.x : k == 1 ? v.y : k == 2 ? v.z : v.w;
}

template <bool ADD>
__global__ __launch_bounds__(256) void conv_k(const float* __restrict__ m,
                                              const float* __restrict__ W1,
                                              const float* __restrict__ b1,
                                              const float* __restrict__ W2,
                                              const float* __restrict__ b2,
                                              const float* __restrict__ hprev,
                                              float* __restrict__ out) {
    __shared__ float4 W1s[1024];  // 64x64
    __shared__ float4 W2s[1024];
    __shared__ float4 b1s[16];
    __shared__ float4 b2s[16];
    const float4* W1g = (const float4*)W1;
    const float4* W2g = (const float4*)W2;
    for (int idx = threadIdx.x; idx < 1024; idx += 256) {
        W1s[idx] = W1g[idx];
        W2s[idx] = W2g[idx];
    }
    if (threadIdx.x < 16)      b1s[threadIdx.x]      = ((const float4*)b1)[threadIdx.x];
    else if (threadIdx.x < 32) b2s[threadIdx.x - 16] = ((const float4*)b2)[threadIdx.x - 16];
    __syncthreads();

    int r = blockIdx.x * blockDim.x + threadIdx.x;
    if (r >= NN) return;
    const float4* mp = (const float4*)(m + (size_t)r * HD);

    float4 t4[16];
#pragma unroll
    for (int j = 0; j < 16; j++) t4[j] = b1s[j];
    for (int k4 = 0; k4 < 16; k4++) {
        float4 mv = mp[k4];
#pragma unroll
        for (int kk = 0; kk < 4; kk++) {
            float mk = f4get(mv, kk);
            const float4* wrow = &W1s[(k4 * 4 + kk) * 16];
#pragma unroll
            for (int j = 0; j < 16; j++) {
                float4 w = wrow[j];
                t4[j].x += mk * w.x; t4[j].y += mk * w.y;
                t4[j].z += mk * w.z; t4[j].w += mk * w.w;
            }
        }
    }
#pragma unroll
    for (int j = 0; j < 16; j++) {
        t4[j].x = fmaxf(t4[j].x, 0.f); t4[j].y = fmaxf(t4[j].y, 0.f);
        t4[j].z = fmaxf(t4[j].z, 0.f); t4[j].w = fmaxf(t4[j].w, 0.f);
    }

    float4 o4[16];
#pragma unroll
    for (int j = 0; j < 16; j++) o4[j] = b2s[j];
#pragma unroll
    for (int k4 = 0; k4 < 16; k4++) {
#pragma unroll
        for (int kk = 0; kk < 4; kk++) {
            float tk = f4get(t4[k4], kk);
            const float4* wrow = &W2s[(k4 * 4 + kk) * 16];
#pragma unroll
            for (int j = 0; j < 16; j++) {
                float4 w = wrow[j];
                o4[j].x += tk * w.x; o4[j].y += tk * w.y;
                o4[j].z += tk * w.z; o4[j].w += tk * w.w;
            }
        }
    }

    float4* op = (float4*)(out + (size_t)r * HD);
    if constexpr (ADD) {
        const float4* hp = (const float4*)(hprev + (size_t)r * HD);
#pragma unroll
        for (int j = 0; j < 16; j++) {
            float4 o = o4[j];
            float4 hv = hp[j];
            o.x += hv.x; o.y += hv.y; o.z += hv.z; o.w += hv.w;
            op[j] = o;
        }
    } else {
#pragma unroll
        for (int j = 0; j < 16; j++) op[j] = o4[j];
    }
}

// ---------------- input linear: h0 = x @ lin_W + lin_b ----------------

__global__ __launch_bounds__(256) void lin_k(const float* __restrict__ x,
                                             const float* __restrict__ W,
                                             const float* __restrict__ b,
                                             float* __restrict__ h0) {
    __shared__ float4 Ws[2048];  // 128x64
    __shared__ float4 bs[16];
    const float4* Wg = (const float4*)W;
    for (int idx = threadIdx.x; idx < 2048; idx += 256) Ws[idx] = Wg[idx];
    if (threadIdx.x < 16) bs[threadIdx.x] = ((const float4*)b)[threadIdx.x];
    __syncthreads();

    int r = blockIdx.x * blockDim.x + threadIdx.x;
    if (r >= NN) return;
    const float4* xp = (const float4*)(x + (size_t)r * FIN);

    float4 t4[16];
#pragma unroll
    for (int j = 0; j < 16; j++) t4[j] = bs[j];
    for (int k4 = 0; k4 < 32; k4++) {
        float4 xv = xp[k4];
#pragma unroll
        for (int kk = 0; kk < 4; kk++) {
            float xk = f4get(xv, kk);
            const float4* wrow = &Ws[(k4 * 4 + kk) * 16];
#pragma unroll
            for (int j = 0; j < 16; j++) {
                float4 w = wrow[j];
                t4[j].x += xk * w.x; t4[j].y += xk * w.y;
                t4[j].z += xk * w.z; t4[j].w += xk * w.w;
            }
        }
    }
    float4* hp = (float4*)(h0 + (size_t)r * HD);
#pragma unroll
    for (int j = 0; j < 16; j++) hp[j] = t4[j];
}

// ---------------- launch ----------------

extern "C" void kernel_launch(void* const* d_in, const int* in_sizes, int n_in,
                              void* d_out, int out_size, void* d_ws, size_t ws_size,
                              hipStream_t stream) {
    (void)in_sizes; (void)n_in; (void)out_size; (void)ws_size;

    const float* x    = (const float*)d_in[0];
    const int*   ei   = (const int*)d_in[1];
    const float* attr = (const float*)d_in[2];
    const float* linW = (const float*)d_in[3];
    const float* linb = (const float*)d_in[4];
    const float* W1   = (const float*)d_in[5];
    const float* b1   = (const float*)d_in[6];
    const float* W2   = (const float*)d_in[7];
    const float* b2   = (const float*)d_in[8];
    float* out = (float*)d_out;

    // workspace layout
    float* h0    = (float*)d_ws;                 // NN*HD
    float* m     = h0 + (size_t)NN * HD;         // NN*HD
    int*   cnt   = (int*)(m + (size_t)NN * HD);  // NN
    int*   off   = cnt + NN;                     // NN+1
    int*   cur   = off + NN + 1;                 // NN
    int*   csrc  = cur + NN;                     // NE
    float* cattr = (float*)(csrc + NE);          // NE

    const int* src = ei;
    const int* dst = ei + NE;

    float* scats = out;
    float* outs  = out + (size_t)SL * NN * HD;

    const size_t NH = (size_t)NN * HD;
    const int EB = (NE + 255) / 256;   // 3125
    const int GB = (NN + 255) / 256;   // 196
    const int WB = (NN * 64) / 256;    // 12500 (wave per node, 4 waves/block)

    // CSR build
    hipMemsetAsync(cnt, 0, NN * sizeof(int), stream);
    hist_k<<<EB, 256, 0, stream>>>(dst, cnt);
    scan_k<<<1, 1024, 0, stream>>>(cnt, off, cur);
    fill_k<<<EB, 256, 0, stream>>>(src, dst, attr, cur, csrc, cattr);

    // h0 = x @ lin_W + lin_b
    lin_k<<<GB, 256, 0, stream>>>(x, linW, linb, h0);

    // layer 0
    scatter_k<<<WB, 256, 0, stream>>>(h0, off, csrc, cattr, m);
    conv_k<true><<<GB, 256, 0, stream>>>(m, W1, b1, W2, b2, h0, outs);

    // scatter(outs0) reused for scats0 (W0) and layer-1 conv (W1)
    scatter_k<<<WB, 256, 0, stream>>>(outs, off, csrc, cattr, m);
    conv_k<false><<<GB, 256, 0, stream>>>(m, W1, b1, W2, b2, nullptr, scats);
    conv_k<true><<<GB, 256, 0, stream>>>(m, W1 + 4096, b1 + 64, W2 + 4096, b2 + 64,
                                         outs, outs + NH);

    // scatter(outs1) reused for scats1 (W1) and layer-2 conv (W2)
    scatter_k<<<WB, 256, 0, stream>>>(outs + NH, off, csrc, cattr, m);
    conv_k<false><<<GB, 256, 0, stream>>>(m, W1 + 4096, b1 + 64, W2 + 4096, b2 + 64,
                                          nullptr, scats + NH);
    conv_k<true><<<GB, 256, 0, stream>>>(m, W1 + 8192, b1 + 128, W2 + 8192, b2 + 128,
                                         outs + NH, outs + 2 * NH);

    // scatter(outs2) for scats2 (W2)
    scatter_k<<<WB, 256, 0, stream>>>(outs + 2 * NH, off, csrc, cattr, m);
    conv_k<false><<<GB, 256, 0, stream>>>(m, W1 + 8192, b1 + 128, W2 + 8192, b2 + 128,
                                          nullptr, scats + 2 * NH);
}

// Round 2
// 471.269 us; speedup vs baseline: 1.2376x; 1.2376x over previous
//
#include <hip/hip_runtime.h>

#define NN 50000
#define NE 800000
#define FIN 128
#define HD 64
#define SL 3
#define NBL 196  // ceil(NN/256)

// ---------------- CSR build ----------------

__global__ void hist_k(const int* __restrict__ dst, int* __restrict__ cnt) {
    int e = blockIdx.x * blockDim.x + threadIdx.x;
    if (e < NE) atomicAdd(&cnt[dst[e]], 1);
}

// block partial sums of cnt
__global__ __launch_bounds__(256) void partial_k(const int* __restrict__ cnt,
                                                 int* __restrict__ partials) {
    __shared__ int sh[256];
    int t = threadIdx.x;
    int idx = blockIdx.x * 256 + t;
    sh[t] = (idx < NN) ? cnt[idx] : 0;
    __syncthreads();
    for (int d = 128; d > 0; d >>= 1) {
        if (t < d) sh[t] += sh[t + d];
        __syncthreads();
    }
    if (t == 0) partials[blockIdx.x] = sh[0];
}

// exclusive scan of the 196 block partials (single small block)
__global__ __launch_bounds__(256) void scanp_k(const int* __restrict__ partials,
                                               int* __restrict__ pscan,
                                               int* __restrict__ off) {
    __shared__ int sh[256];
    int t = threadIdx.x;
    int v = (t < NBL) ? partials[t] : 0;
    sh[t] = v;
    __syncthreads();
    for (int d = 1; d < 256; d <<= 1) {
        int u = (t >= d) ? sh[t - d] : 0;
        __syncthreads();
        sh[t] += u;
        __syncthreads();
    }
    if (t < NBL) pscan[t] = sh[t] - v;  // exclusive
    if (t == 255) off[NN] = sh[255];    // total = NE
}

// per-block exclusive scan + global offset -> off, cur
__global__ __launch_bounds__(256) void offs_k(const int* __restrict__ cnt,
                                              const int* __restrict__ pscan,
                                              int* __restrict__ off,
                                              int* __restrict__ cur) {
    __shared__ int sh[256];
    int t = threadIdx.x;
    int idx = blockIdx.x * 256 + t;
    int v = (idx < NN) ? cnt[idx] : 0;
    sh[t] = v;
    __syncthreads();
    for (int d = 1; d < 256; d <<= 1) {
        int u = (t >= d) ? sh[t - d] : 0;
        __syncthreads();
        sh[t] += u;
        __syncthreads();
    }
    if (idx < NN) {
        int o = pscan[blockIdx.x] + sh[t] - v;  // exclusive
        off[idx] = o;
        cur[idx] = o;
    }
}

__global__ void fill_k(const int* __restrict__ src, const int* __restrict__ dst,
                       const float* __restrict__ attr, int* __restrict__ cur,
                       int* __restrict__ csrc, float* __restrict__ cattr) {
    int e = blockIdx.x * blockDim.x + threadIdx.x;
    if (e < NE) {
        int d = dst[e];
        int p = atomicAdd(&cur[d], 1);
        csrc[p]  = src[e];
        cattr[p] = attr[e];
    }
}

// ---------------- scatter: m[n] = sum_{e: dst=n} attr[e] * h[src[e]] ----------------
// wave per dst node; lane = feature. No atomics: CSR gives exclusive writes.

__global__ __launch_bounds__(256) void scatter_k(const float* __restrict__ h,
                                                 const int* __restrict__ off,
                                                 const int* __restrict__ csrc,
                                                 const float* __restrict__ cattr,
                                                 float* __restrict__ m) {
    int w    = (blockIdx.x * blockDim.x + threadIdx.x) >> 6;
    int lane = threadIdx.x & 63;
    if (w >= NN) return;
    int s = off[w], e = off[w + 1];
    float acc = 0.f;
    int i = s;
    for (; i + 4 <= e; i += 4) {
        int   s0 = csrc[i],     s1 = csrc[i + 1], s2 = csrc[i + 2], s3 = csrc[i + 3];
        float a0 = cattr[i],    a1 = cattr[i + 1], a2 = cattr[i + 2], a3 = cattr[i + 3];
        float v0 = h[(size_t)s0 * HD + lane];
        float v1 = h[(size_t)s1 * HD + lane];
        float v2 = h[(size_t)s2 * HD + lane];
        float v3 = h[(size_t)s3 * HD + lane];
        acc += a0 * v0;
        acc += a1 * v1;
        acc += a2 * v2;
        acc += a3 * v3;
    }
    for (; i < e; ++i) acc += cattr[i] * h[(size_t)csrc[i] * HD + lane];
    m[(size_t)w * HD + lane] = acc;
}

// ---------------- conv GEMM stage: out = [hprev +] relu(m@W1+b1)@W2+b2 ----------------

__device__ __forceinline__ float f4get(const float4 v, int k) {
    return k == 0 ? v.x : k == 1 ? v.y : k == 2 ? v.z : v.w;
}

template <bool ADD>
__global__ __launch_bounds__(256) void conv_k(const float* __restrict__ m,
                                              const float* __restrict__ W1,
                                              const float* __restrict__ b1,
                                              const float* __restrict__ W2,
                                              const float* __restrict__ b2,
                                              const float* __restrict__ hprev,
                                              float* __restrict__ out) {
    __shared__ float4 W1s[1024];  // 64x64
    __shared__ float4 W2s[1024];
    __shared__ float4 b1s[16];
    __shared__ float4 b2s[16];
    const float4* W1g = (const float4*)W1;
    const float4* W2g = (const float4*)W2;
    for (int idx = threadIdx.x; idx < 1024; idx += 256) {
        W1s[idx] = W1g[idx];
        W2s[idx] = W2g[idx];
    }
    if (threadIdx.x < 16)      b1s[threadIdx.x]      = ((const float4*)b1)[threadIdx.x];
    else if (threadIdx.x < 32) b2s[threadIdx.x - 16] = ((const float4*)b2)[threadIdx.x - 16];
    __syncthreads();

    int r = blockIdx.x * blockDim.x + threadIdx.x;
    if (r >= NN) return;
    const float4* mp = (const float4*)(m + (size_t)r * HD);

    float4 t4[16];
#pragma unroll
    for (int j = 0; j < 16; j++) t4[j] = b1s[j];
    for (int k4 = 0; k4 < 16; k4++) {
        float4 mv = mp[k4];
#pragma unroll
        for (int kk = 0; kk < 4; kk++) {
            float mk = f4get(mv, kk);
            const float4* wrow = &W1s[(k4 * 4 + kk) * 16];
#pragma unroll
            for (int j = 0; j < 16; j++) {
                float4 w = wrow[j];
                t4[j].x += mk * w.x; t4[j].y += mk * w.y;
                t4[j].z += mk * w.z; t4[j].w += mk * w.w;
            }
        }
    }
#pragma unroll
    for (int j = 0; j < 16; j++) {
        t4[j].x = fmaxf(t4[j].x, 0.f); t4[j].y = fmaxf(t4[j].y, 0.f);
        t4[j].z = fmaxf(t4[j].z, 0.f); t4[j].w = fmaxf(t4[j].w, 0.f);
    }

    float4 o4[16];
#pragma unroll
    for (int j = 0; j < 16; j++) o4[j] = b2s[j];
#pragma unroll
    for (int k4 = 0; k4 < 16; k4++) {
#pragma unroll
        for (int kk = 0; kk < 4; kk++) {
            float tk = f4get(t4[k4], kk);
            const float4* wrow = &W2s[(k4 * 4 + kk) * 16];
#pragma unroll
            for (int j = 0; j < 16; j++) {
                float4 w = wrow[j];
                o4[j].x += tk * w.x; o4[j].y += tk * w.y;
                o4[j].z += tk * w.z; o4[j].w += tk * w.w;
            }
        }
    }

    float4* op = (float4*)(out + (size_t)r * HD);
    if constexpr (ADD) {
        const float4* hp = (const float4*)(hprev + (size_t)r * HD);
#pragma unroll
        for (int j = 0; j < 16; j++) {
            float4 o = o4[j];
            float4 hv = hp[j];
            o.x += hv.x; o.y += hv.y; o.z += hv.z; o.w += hv.w;
            op[j] = o;
        }
    } else {
#pragma unroll
        for (int j = 0; j < 16; j++) op[j] = o4[j];
    }
}

// ---------------- input linear: h0 = x @ lin_W + lin_b ----------------

__global__ __launch_bounds__(256) void lin_k(const float* __restrict__ x,
                                             const float* __restrict__ W,
                                             const float* __restrict__ b,
                                             float* __restrict__ h0) {
    __shared__ float4 Ws[2048];  // 128x64
    __shared__ float4 bs[16];
    const float4* Wg = (const float4*)W;
    for (int idx = threadIdx.x; idx < 2048; idx += 256) Ws[idx] = Wg[idx];
    if (threadIdx.x < 16) bs[threadIdx.x] = ((const float4*)b)[threadIdx.x];
    __syncthreads();

    int r = blockIdx.x * blockDim.x + threadIdx.x;
    if (r >= NN) return;
    const float4* xp = (const float4*)(x + (size_t)r * FIN);

    float4 t4[16];
#pragma unroll
    for (int j = 0; j < 16; j++) t4[j] = bs[j];
    for (int k4 = 0; k4 < 32; k4++) {
        float4 xv = xp[k4];
#pragma unroll
        for (int kk = 0; kk < 4; kk++) {
            float xk = f4get(xv, kk);
            const float4* wrow = &Ws[(k4 * 4 + kk) * 16];
#pragma unroll
            for (int j = 0; j < 16; j++) {
                float4 w = wrow[j];
                t4[j].x += xk * w.x; t4[j].y += xk * w.y;
                t4[j].z += xk * w.z; t4[j].w += xk * w.w;
            }
        }
    }
    float4* hp = (float4*)(h0 + (size_t)r * HD);
#pragma unroll
    for (int j = 0; j < 16; j++) hp[j] = t4[j];
}

// ---------------- launch ----------------

extern "C" void kernel_launch(void* const* d_in, const int* in_sizes, int n_in,
                              void* d_out, int out_size, void* d_ws, size_t ws_size,
                              hipStream_t stream) {
    (void)in_sizes; (void)n_in; (void)out_size; (void)ws_size;

    const float* x    = (const float*)d_in[0];
    const int*   ei   = (const int*)d_in[1];
    const float* attr = (const float*)d_in[2];
    const float* linW = (const float*)d_in[3];
    const float* linb = (const float*)d_in[4];
    const float* W1   = (const float*)d_in[5];
    const float* b1   = (const float*)d_in[6];
    const float* W2   = (const float*)d_in[7];
    const float* b2   = (const float*)d_in[8];
    float* out = (float*)d_out;

    // workspace layout
    float* h0      = (float*)d_ws;                 // NN*HD
    float* m       = h0 + (size_t)NN * HD;         // NN*HD
    int*   cnt     = (int*)(m + (size_t)NN * HD);  // NN
    int*   off     = cnt + NN;                     // NN+1
    int*   cur     = off + NN + 1;                 // NN
    int*   parts   = cur + NN;                     // 256
    int*   pscan   = parts + 256;                  // 256
    int*   csrc    = pscan + 256;                  // NE
    float* cattr   = (float*)(csrc + NE);          // NE

    const int* src = ei;
    const int* dst = ei + NE;

    float* scats = out;
    float* outs  = out + (size_t)SL * NN * HD;

    const size_t NH = (size_t)NN * HD;
    const int EB = (NE + 255) / 256;   // 3125
    const int GB = (NN + 255) / 256;   // 196
    const int WB = (NN * 64) / 256;    // 12500 (wave per node, 4 waves/block)

    // CSR build (device-wide 3-pass scan; old single-block scan was 125 us)
    hipMemsetAsync(cnt, 0, NN * sizeof(int), stream);
    hist_k<<<EB, 256, 0, stream>>>(dst, cnt);
    partial_k<<<NBL, 256, 0, stream>>>(cnt, parts);
    scanp_k<<<1, 256, 0, stream>>>(parts, pscan, off);
    offs_k<<<NBL, 256, 0, stream>>>(cnt, pscan, off, cur);
    fill_k<<<EB, 256, 0, stream>>>(src, dst, attr, cur, csrc, cattr);

    // h0 = x @ lin_W + lin_b
    lin_k<<<GB, 256, 0, stream>>>(x, linW, linb, h0);

    // layer 0
    scatter_k<<<WB, 256, 0, stream>>>(h0, off, csrc, cattr, m);
    conv_k<true><<<GB, 256, 0, stream>>>(m, W1, b1, W2, b2, h0, outs);

    // scatter(outs0) reused for scats0 (W0) and layer-1 conv (W1)
    scatter_k<<<WB, 256, 0, stream>>>(outs, off, csrc, cattr, m);
    conv_k<false><<<GB, 256, 0, stream>>>(m, W1, b1, W2, b2, nullptr, scats);
    conv_k<true><<<GB, 256, 0, stream>>>(m, W1 + 4096, b1 + 64, W2 + 4096, b2 + 64,
                                         outs, outs + NH);

    // scatter(outs1) reused for scats1 (W1) and layer-2 conv (W2)
    scatter_k<<<WB, 256, 0, stream>>>(outs + NH, off, csrc, cattr, m);
    conv_k<false><<<GB, 256, 0, stream>>>(m, W1 + 4096, b1 + 64, W2 + 4096, b2 + 64,
                                          nullptr, scats + NH);
    conv_k<true><<<GB, 256, 0, stream>>>(m, W1 + 8192, b1 + 128, W2 + 8192, b2 + 128,
                                         outs + NH, outs + 2 * NH);

    // scatter(outs2) for scats2 (W2)
    scatter_k<<<WB, 256, 0, stream>>>(outs + 2 * NH, off, csrc, cattr, m);
    conv_k<false><<<GB, 256, 0, stream>>>(m, W1 + 8192, b1 + 128, W2 + 8192, b2 + 128,
                                          nullptr, scats + 2 * NH);
}